// Round 8
// baseline (86.470 us; speedup 1.0000x reference)
//
#include <hip/hip_runtime.h>
#include <hip/hip_bf16.h>
#include <hip/hip_fp8.h>

typedef __attribute__((ext_vector_type(4))) float f32x4;
typedef long long i64;

// exp(v/T - 5) with T=0.2  ==  exp2( (v-1) * 5*log2(e) )
#define EXP_SCALE 7.213475204444817f

__device__ __forceinline__ float fast_exp2(float x) {
#if __has_builtin(__builtin_amdgcn_exp2f)
  return __builtin_amdgcn_exp2f(x);
#else
  return exp2f(x);
#endif
}

// z is stored as fp8 e4m3, SWIZZLED in MFMA-fragment order (byte units):
//   byte addr = tile*2048 + kk*512 + slot*8 + rem
// tile = row>>4, c = row&15; element e: kk = e>>5, q = (e>>3)&3, rem = e&7,
// slot = q*16 + c. A wave (lane = q*16+c) loads one (tile,kk) fragment as
// one contiguous 512B read (8B/lane).

// Kernel 1: L2-normalize rows -> swizzled fp8 z. Zeroes out[0].
__global__ __launch_bounds__(256) void k_normalize(
    const float* __restrict__ emb_i, const float* __restrict__ emb_j,
    unsigned char* __restrict__ z, float* __restrict__ out)
{
  if (blockIdx.x == 0 && threadIdx.x == 0) out[0] = 0.0f;
  const int t = threadIdx.x;
  const int c = t >> 4;               // row within tile (0..15)
  const int sub = t & 15;             // 8-element block within row
  const int row = (blockIdx.x << 4) + c;
  const float* src = (row < 4096) ? (emb_i + row * 128) : (emb_j + (row - 4096) * 128);
  float4 v0 = reinterpret_cast<const float4*>(src)[sub * 2];
  float4 v1 = reinterpret_cast<const float4*>(src)[sub * 2 + 1];
  float ss = v0.x*v0.x + v0.y*v0.y + v0.z*v0.z + v0.w*v0.w
           + v1.x*v1.x + v1.y*v1.y + v1.z*v1.z + v1.w*v1.w;
  #pragma unroll
  for (int m = 1; m < 16; m <<= 1) ss += __shfl_xor(ss, m, 64);
  float rinv = 1.0f / sqrtf(ss);
  unsigned char st[8];
  st[0] = __hip_fp8_e4m3(v0.x * rinv).__x;
  st[1] = __hip_fp8_e4m3(v0.y * rinv).__x;
  st[2] = __hip_fp8_e4m3(v0.z * rinv).__x;
  st[3] = __hip_fp8_e4m3(v0.w * rinv).__x;
  st[4] = __hip_fp8_e4m3(v1.x * rinv).__x;
  st[5] = __hip_fp8_e4m3(v1.y * rinv).__x;
  st[6] = __hip_fp8_e4m3(v1.z * rinv).__x;
  st[7] = __hip_fp8_e4m3(v1.w * rinv).__x;
  unsigned char* dst = z + blockIdx.x * 2048 + (sub >> 2) * 512 +
                       (((sub & 3) << 4) + c) * 8;
  *reinterpret_cast<i64*>(dst) = *reinterpret_cast<i64*>(st);
}

// Kernel 2 (symmetric, fp8 MFMA), atomic-free, LDS-SHARED PANELS.
// Cell = 256 rows x 512 cols; 1024-thread block = 16 waves
// (4 rowgroups g x 4 col-walks cw). For chunk ch: rb = 0..2(ch+1)-1,
// start(ch) = ch(ch+1) -> 272 cells (53% of full work).
// Block stages A-panel (32KB) + B-panel (64KB) into LDS ONCE; waves read
// fragments from LDS. Global traffic 26 MB total vs 102 MB register-B
// (rounds 5-7 A/B: k_simlse wall time scales with panel traffic at
// ~5 TB/s effective; shape/pipeline variants were null).
// upper iff rb < 2ch: transposed col-sums -> cpart slot (ch,rb,g,col),
// unique. Row-sums -> rpart[ch][row], unique. Diagonal exp term (==1)
// kept; k_finish subtracts 1. Per-wave math = round-5/7-verified body.
__global__ __launch_bounds__(1024, 4) void k_simlse(
    const unsigned char* __restrict__ z,
    float* __restrict__ rpart,    // [16][8192] row partial sums
    float* __restrict__ cpart,    // packed col partials, 491520 floats
    float* __restrict__ rowpos)   // [8192]; only [0..4095] consumed
{
  const int w = threadIdx.x >> 6;
  const int g = w >> 2;               // rowgroup (0..3): rows R0+64g..+63
  const int cw = w & 3;               // column-walk wave (0..3)
  const int lane = threadIdx.x & 63;
  const int q = lane >> 4;
  const int c = lane & 15;
  const int bid = blockIdx.x;

  // closed-form ch from start(ch) = ch(ch+1); integer fixups guard rounding.
  int ch = (int)((sqrtf((float)(4 * bid + 1)) - 1.0f) * 0.5f);
  if (bid >= (ch + 1) * (ch + 2)) ++ch;
  else if (bid < ch * (ch + 1)) --ch;
  const int rb = bid - ch * (ch + 1);              // 0 .. 2(ch+1)-1
  const int R0 = rb << 8;                          // 256-row block
  const bool upper = (rb < (ch << 1));             // strictly above diagonal band

  // ---- stage A-panel (32KB: tiles R0>>4 .. +15) then B-panel (64KB:
  // tiles 32ch .. 32ch+31) into LDS; both are contiguous in z. 16B/thread
  // x 6 slices, coalesced. j=0,1 -> A; j=2..5 -> B (branch uniform per j).
  __shared__ unsigned char sz[98304];              // A | B
  __shared__ float lsum[16][64];
  __shared__ float lpos[16][16];
  {
    const unsigned char* zA = z + (R0 >> 4) * 2048;
    const unsigned char* zB = z + ch * 65536;
    #pragma unroll
    for (int j = 0; j < 6; ++j) {
      const int off = j * 16384 + threadIdx.x * 16;
      const unsigned char* src = (j < 2) ? (zA + off) : (zB + (off - 32768));
      *reinterpret_cast<int4*>(&sz[off]) = *reinterpret_cast<const int4*>(src);
    }
  }
  __syncthreads();

  // ---- A fragments for this wave's 64-row group: 16 ds_reads ----
  i64 a[4][4];
  #pragma unroll
  for (int rg = 0; rg < 4; ++rg)
    #pragma unroll
    for (int kk = 0; kk < 4; ++kk)
      a[rg][kk] = *reinterpret_cast<const i64*>(
          sz + ((g << 2) + rg) * 2048 + kk * 512 + (lane << 3));

  float acc[4][4];
  #pragma unroll
  for (int rg = 0; rg < 4; ++rg)
    #pragma unroll
    for (int e = 0; e < 4; ++e) acc[rg][e] = 0.0f;
  float pacc[4] = {0.f, 0.f, 0.f, 0.f};
  float colp[8];
  #pragma unroll
  for (int i = 0; i < 8; ++i) colp[i] = 0.0f;

  // positive tiles: pos0t is 16-aligned -> all 16 of this cell's pos tiles
  // share one 32-tile chunk; ownership iff that chunk == ch. Wave (g,cw)
  // meets its pos tile (pos0t + 4g + cw) at walk index ipb0 + g, in
  // A-subtile rr == cw. ipb0 = ((pos0t&31)>>2) in {0,4} so ipb0+g <= 7.
  const int pos0t = ((R0 + 4096) & 8191) >> 4;
  const bool haspos = ((pos0t >> 5) == ch);
  const int ipb = haspos ? ((pos0t & 31) >> 2) + g : -99;

  i64 b0[4], b1[4];
  auto ldb = [&](i64 (&dst)[4], int idx) {      // B tile local (cw + 4*idx)
    const unsigned char* p = sz + 32768 + (cw + (idx << 2)) * 2048 + (lane << 3);
    dst[0] = *reinterpret_cast<const i64*>(p);
    dst[1] = *reinterpret_cast<const i64*>(p + 512);
    dst[2] = *reinterpret_cast<const i64*>(p + 1024);
    dst[3] = *reinterpret_cast<const i64*>(p + 1536);
  };

  auto process = [&](const i64 (&bb)[4], int i) {
    f32x4 cc[4];
    #pragma unroll
    for (int rr = 0; rr < 4; ++rr) cc[rr] = f32x4{0.f, 0.f, 0.f, 0.f};
    #pragma unroll
    for (int kk = 0; kk < 4; ++kk)
      #pragma unroll
      for (int rr = 0; rr < 4; ++rr)
        cc[rr] = __builtin_amdgcn_mfma_f32_16x16x32_fp8_fp8(
            a[rr][kk], bb[kk], cc[rr], 0, 0, 0);
    float cp0 = 0.0f, cp1 = 0.0f;       // two chains to cut dep latency
    #pragma unroll
    for (int rr = 0; rr < 4; ++rr)
      #pragma unroll
      for (int e = 0; e < 4; ++e) {
        float tv = fast_exp2(__builtin_fmaf(cc[rr][e], EXP_SCALE, -EXP_SCALE));
        acc[rr][e] += tv;
        if (upper) { if (rr & 1) cp1 += tv; else cp0 += tv; }
      }
    if (upper) colp[i] = cp0 + cp1;     // shfl deferred out of the loop
    if (i == ipb) {                     // rare, wave-uniform
      #pragma unroll
      for (int rr = 0; rr < 4; ++rr) {
        if (rr == cw) {
          #pragma unroll
          for (int e = 0; e < 4; ++e)
            if (c == ((q << 2) + e)) pacc[e] = cc[rr][e] * 5.0f;
        }
      }
    }
  };

  ldb(b0, 0);
  #pragma unroll 1
  for (int i = 0; i < 8; i += 2) {
    ldb(b1, i + 1);
    process(b0, i);
    if (i + 2 < 8) ldb(b0, i + 2);
    process(b1, i + 1);
  }

  // Deferred colsum reduction -> PLAIN stores into this cell's private slice
  if (upper) {
    const int cbase = 2048 * ch * (ch - 1) + (((rb << 2) + g) << 9);
    #pragma unroll
    for (int j = 0; j < 8; ++j) {
      float v = colp[j];
      v += __shfl_xor(v, 16, 64);
      v += __shfl_xor(v, 32, 64);
      if (lane < 16)                    // local col = (cw + 4j)*16 + c
        cpart[cbase + ((cw + (j << 2)) << 4) + c] = v;
    }
  }

  // Reduce row-sums over the 16 cols per tile (c-group: xor 1,2,4,8)
  #pragma unroll
  for (int m = 1; m < 16; m <<= 1) {
    #pragma unroll
    for (int rg = 0; rg < 4; ++rg)
      #pragma unroll
      for (int e = 0; e < 4; ++e)
        acc[rg][e] += __shfl_xor(acc[rg][e], m, 64);
    #pragma unroll
    for (int e = 0; e < 4; ++e) pacc[e] += __shfl_xor(pacc[e], m, 64);
  }

  if (c == 0) {
    #pragma unroll
    for (int rg = 0; rg < 4; ++rg)
      #pragma unroll
      for (int e = 0; e < 4; ++e)
        lsum[w][rg * 16 + (q << 2) + e] = acc[rg][e];
    #pragma unroll
    for (int e = 0; e < 4; ++e) lpos[w][(q << 2) + e] = pacc[e];
  }
  __syncthreads();

  if (threadIdx.x < 256) {
    const int t = threadIdx.x;            // row R0 + t
    const int gg = t >> 6, tr = t & 63;
    float s = lsum[(gg << 2) + 0][tr] + lsum[(gg << 2) + 1][tr]
            + lsum[(gg << 2) + 2][tr] + lsum[(gg << 2) + 3][tr];
    rpart[(ch << 13) + R0 + t] = s;       // plain store, unique (ch,row) slot
    if (haspos)                           // R0>=4096 cells write the mirror
      rowpos[R0 + t] = lpos[(gg << 2) + ((t >> 4) & 3)][t & 15];
  }                                       // half (rowpos[>=4096], unused)
}

// Kernel 3: gather partials. rowsum[r] = sum_{ch=r>>9}^{15} rpart[ch][r]
//   + sum_{k=0}^{8*(r>>9)-1} cpart[2048*chr*(chr-1) + k*512 + (r&511)]
// (k enumerates (rb,g); every summed slot written by an existing cell; no
// zero-init needed). tot = rowsum - 1; lse = 5 + log(tot);
// loss = mean(lse - pos), pos mirrored via r & 4095.
__global__ __launch_bounds__(256) void k_finish(
    const float* __restrict__ rpart, const float* __restrict__ cpart,
    const float* __restrict__ rowpos, float* __restrict__ out)
{
  const int r = blockIdx.x * 256 + threadIdx.x;
  const int chr = r >> 9;

  float rs = 0.0f;
  #pragma unroll 4
  for (int ch = chr; ch < 16; ++ch) rs += rpart[(ch << 13) + r];

  const int nv = chr << 3;                         // multiple of 8
  const float* cb = cpart + 2048 * chr * (chr - 1) + (r & 511);
  float cs0 = 0.f, cs1 = 0.f, cs2 = 0.f, cs3 = 0.f;
  #pragma unroll 2
  for (int k = 0; k < nv; k += 4) {
    cs0 += cb[(k + 0) << 9];
    cs1 += cb[(k + 1) << 9];
    cs2 += cb[(k + 2) << 9];
    cs3 += cb[(k + 3) << 9];
  }

  float tot = rs + ((cs0 + cs1) + (cs2 + cs3)) - 1.0f;
  float v = 5.0f + logf(tot) - rowpos[r & 4095];
  #pragma unroll
  for (int m = 1; m < 64; m <<= 1) v += __shfl_xor(v, m, 64);
  __shared__ float red[4];
  if ((threadIdx.x & 63) == 0) red[threadIdx.x >> 6] = v;
  __syncthreads();
  if (threadIdx.x == 0)
    atomicAdd(out, (red[0] + red[1] + red[2] + red[3]) * (1.0f / 8192.0f));
}

extern "C" void kernel_launch(void* const* d_in, const int* in_sizes, int n_in,
                              void* d_out, int out_size, void* d_ws, size_t ws_size,
                              hipStream_t stream) {
  const float* emb_i = (const float*)d_in[0];
  const float* emb_j = (const float*)d_in[1];
  unsigned char* z = (unsigned char*)d_ws;                   // 1 MB fp8, swizzled
  float* rpart = (float*)((char*)d_ws + (1 << 20));          // 16*8192*4 = 512 KB
  float* cpart = (float*)((char*)d_ws + 1572864);            // 491520 floats = 1.875 MB
  float* rowpos = (float*)((char*)d_ws + 3538944);           // [8192] = 32 KB
  float* out = (float*)d_out;

  k_normalize<<<512, 256, 0, stream>>>(emb_i, emb_j, z, out);
  k_simlse<<<272, 1024, 0, stream>>>(z, rpart, cpart, rowpos);
  k_finish<<<32, 256, 0, stream>>>(rpart, cpart, rowpos, out);
}